// Round 1
// baseline (506.346 us; speedup 1.0000x reference)
//
#include <hip/hip_runtime.h>
#include <stdint.h>

// OhemPairTripletLoss on MI355X (gfx950)
// loss[i,j] = relu(a_i - b_j + 2*c_ij),  c = pair1 @ pair2^T (K=128)
//   b_j = ||pair2_j||^2,  a_i = b_i - 2*c_ii + MARGIN
// out[0] = avg of top-512 distinct losses (dup set top-1024), out[1] = sum/(N*(N-1))

#define NROWS 8192
#define DDIM  128
#define MARGIN_F 0.3f
#define HALFK 512
#define HIST_BINS 2048
#define HIST_MIN 96.0f
#define NCOPY 64
#define CAND_CAP 8192

typedef unsigned short u16;
typedef short bf16x8 __attribute__((ext_vector_type(8)));
typedef float f32x4 __attribute__((ext_vector_type(4)));

// ws layout (bytes)
#define OFF_P1B  0
#define OFF_P2B  (2*1024*1024)
#define OFF_AARR (4*1024*1024)
#define OFF_BARR (OFF_AARR + 32768)
#define OFF_HIST (OFF_BARR + 32768)
#define OFF_CNT  (OFF_HIST + NCOPY*HIST_BINS*4)
#define OFF_CAND (OFF_CNT + 64)
// counters: [0] S_total f32, [1] P int, [2] cand_cnt int, [3] mode int, [4] T f32

__global__ void init_kernel(int* zbase) {
    const int n = NCOPY*HIST_BINS + 16;  // hist + counters (contiguous)
    for (int i = blockIdx.x*blockDim.x + threadIdx.x; i < n; i += gridDim.x*blockDim.x)
        zbase[i] = 0;
}

__device__ __forceinline__ u16 f2bf(float f) {
    unsigned int u = __float_as_uint(f);
    u = (u + 0x7FFFu + ((u >> 16) & 1u)) >> 16;
    return (u16)u;
}

// one wave per row: bf16 convert + b_j = ||p2_j||^2, a_i = b_i - 2*c_ii + margin
__global__ __launch_bounds__(256) void prep_kernel(
    const float* __restrict__ p1, const float* __restrict__ p2,
    u16* __restrict__ p1b, u16* __restrict__ p2b,
    float* __restrict__ aArr, float* __restrict__ bArr)
{
    const int wid = threadIdx.x >> 6, lane = threadIdx.x & 63;
    const int row = blockIdx.x*4 + wid;
    const float2 v1 = *(const float2*)&p1[row*DDIM + lane*2];
    const float2 v2 = *(const float2*)&p2[row*DDIM + lane*2];
    u16 a0 = f2bf(v1.x), a1 = f2bf(v1.y), b0 = f2bf(v2.x), b1 = f2bf(v2.y);
    *(u16*)&p1b[row*DDIM + lane*2]     = a0;
    *(u16*)&p1b[row*DDIM + lane*2 + 1] = a1;
    *(u16*)&p2b[row*DDIM + lane*2]     = b0;
    *(u16*)&p2b[row*DDIM + lane*2 + 1] = b1;
    float sq = v2.x*v2.x + v2.y*v2.y;
    float cp = v1.x*v2.x + v1.y*v2.y;
    #pragma unroll
    for (int off = 32; off > 0; off >>= 1) {
        sq += __shfl_down(sq, off);
        cp += __shfl_down(cp, off);
    }
    if (lane == 0) {
        bArr[row] = sq;
        aArr[row] = sq - 2.0f*cp + MARGIN_F;
    }
}

// 128x128 tile, 4 waves (2x2), 16x16x32 bf16 MFMA, K=128 in one shot.
// PASS 1: sum + positive count + tail histogram.  PASS 3: collect values >= T.
template<int PASS>
__global__ __launch_bounds__(256, 2) void pair_gemm(
    const u16* __restrict__ p1b, const u16* __restrict__ p2b,
    const float* __restrict__ aArr, const float* __restrict__ bArr,
    float* __restrict__ S_total, int* __restrict__ P_total,
    int* __restrict__ hist,
    const int* __restrict__ modePtr, const float* __restrict__ Tptr,
    int* __restrict__ candCnt, float* __restrict__ cand)
{
    if (PASS == 3) {
        int m = *modePtr;
        if (m != 1 && m != 3) return;   // uniform early-exit
    }
    __shared__ u16 At[128][136];   // +8 pad: breaks 256B-stride bank conflicts
    __shared__ u16 Bt[128][136];
    const int tid = threadIdx.x;
    const int bi = blockIdx.y, bj = blockIdx.x;
    const int i0 = bi*128, j0 = bj*128;
    #pragma unroll
    for (int it = 0; it < 8; ++it) {
        int c = tid + it*256;
        int r = c >> 4, cc = (c & 15) * 8;
        *(uint4*)&At[r][cc] = *(const uint4*)&p1b[(i0 + r)*DDIM + cc];
        *(uint4*)&Bt[r][cc] = *(const uint4*)&p2b[(j0 + r)*DDIM + cc];
    }
    __syncthreads();
    const int lane = tid & 63, wid = tid >> 6;
    const int r16 = lane & 15, hi = lane >> 4;
    const int wm = (wid >> 1)*64, wn = (wid & 1)*64;
    f32x4 acc[4][4];
    #pragma unroll
    for (int a = 0; a < 4; ++a)
        #pragma unroll
        for (int b = 0; b < 4; ++b) acc[a][b] = (f32x4){0.f, 0.f, 0.f, 0.f};
    #pragma unroll
    for (int ks = 0; ks < 4; ++ks) {
        const int kc = ks*32 + hi*8;
        bf16x8 aF[4], bF[4];
        #pragma unroll
        for (int mi = 0; mi < 4; ++mi) aF[mi] = *(const bf16x8*)&At[wm + mi*16 + r16][kc];
        #pragma unroll
        for (int ni = 0; ni < 4; ++ni) bF[ni] = *(const bf16x8*)&Bt[wn + ni*16 + r16][kc];
        #pragma unroll
        for (int mi = 0; mi < 4; ++mi)
            #pragma unroll
            for (int ni = 0; ni < 4; ++ni)
                acc[mi][ni] = __builtin_amdgcn_mfma_f32_16x16x32_bf16(aF[mi], bF[ni], acc[mi][ni], 0, 0, 0);
    }
    // epilogue: loss = a_i - b_j + 2*c_ij, relu, skip diagonal
    float bv[4], av[4][4];
    #pragma unroll
    for (int ni = 0; ni < 4; ++ni) bv[ni] = bArr[j0 + wn + ni*16 + r16];
    #pragma unroll
    for (int mi = 0; mi < 4; ++mi)
        #pragma unroll
        for (int r = 0; r < 4; ++r) av[mi][r] = aArr[i0 + wm + mi*16 + hi*4 + r];
    float Tthr = 0.f;
    if (PASS == 3) Tthr = *Tptr;
    float lsum = 0.f; int pcnt = 0;
    int* myhist = hist + ((bi*64 + bj) & (NCOPY - 1))*HIST_BINS;
    #pragma unroll
    for (int mi = 0; mi < 4; ++mi) {
        #pragma unroll
        for (int ni = 0; ni < 4; ++ni) {
            #pragma unroll
            for (int r = 0; r < 4; ++r) {
                int ii = i0 + wm + mi*16 + hi*4 + r;
                int jj = j0 + wn + ni*16 + r16;
                float v = av[mi][r] - bv[ni] + 2.0f*acc[mi][ni][r];
                bool valid = (v > 0.f) && (ii != jj);
                if (PASS == 1) {
                    if (valid) {
                        lsum += v; pcnt++;
                        if (v >= HIST_MIN) {
                            int bin = (int)((v - HIST_MIN) * 4.0f);
                            if (bin > HIST_BINS - 1) bin = HIST_BINS - 1;
                            atomicAdd(&myhist[bin], 1);
                        }
                    }
                } else {
                    if (valid && v >= Tthr) {
                        int idx = atomicAdd(candCnt, 1);
                        if (idx < CAND_CAP) cand[idx] = v;
                    }
                }
            }
        }
    }
    if (PASS == 1) {
        #pragma unroll
        for (int off = 32; off > 0; off >>= 1) {
            lsum += __shfl_down(lsum, off);
            pcnt += __shfl_down(pcnt, off);
        }
        if (lane == 0) {
            atomicAdd(S_total, lsum);
            atomicAdd(P_total, pcnt);
        }
    }
}

// single block: merge histogram copies, find exact threshold bin for top-512
__global__ __launch_bounds__(256) void scan_kernel(
    const int* __restrict__ hist, const int* __restrict__ P_total,
    int* __restrict__ modePtr, float* __restrict__ Tptr)
{
    __shared__ int h[HIST_BINS];
    __shared__ int chunk[256];
    const int tid = threadIdx.x;
    for (int b = tid; b < HIST_BINS; b += 256) {
        int s = 0;
        for (int c = 0; c < NCOPY; ++c) s += hist[c*HIST_BINS + b];
        h[b] = s;
    }
    __syncthreads();
    int cs = 0;
    #pragma unroll
    for (int k = 0; k < 8; ++k) cs += h[tid*8 + k];
    chunk[tid] = cs;
    __syncthreads();
    if (tid == 0) {
        int total = 0;
        for (int t = 0; t < 256; ++t) total += chunk[t];
        int run = 0, found = 0, Tbin = 0;
        for (int t = 255; t >= 0 && !found; --t) {
            if (run + chunk[t] >= HALFK) {
                for (int b = t*8 + 7; b >= t*8; --b) {
                    run += h[b];
                    if (run >= HALFK) { Tbin = b; found = 1; break; }
                }
            } else run += chunk[t];
        }
        // defensive: keep candidate count within buffer capacity
        while (found && run > CAND_CAP && Tbin < HIST_BINS - 1) { run -= h[Tbin]; Tbin++; }
        int P = *P_total;
        int mode; float T = 0.f;
        if (total >= HALFK && found) { mode = 1; T = HIST_MIN + (float)Tbin * 0.25f; }
        else if (P >= HALFK)         { mode = 3; T = 1e-30f; }
        else if (P > 0)              { mode = 2; }
        else                          mode = 0;
        *modePtr = mode; *Tptr = T;
    }
}

// single block: exact top-512 selection over candidates, write outputs
__global__ __launch_bounds__(1024) void select_kernel(
    const int* __restrict__ modePtr, const float* __restrict__ S_total_f,
    const int* __restrict__ P_total, const int* __restrict__ candCnt,
    const float* __restrict__ cand, float* __restrict__ out)
{
    __shared__ float vals[CAND_CAP];
    __shared__ float wsum[16];
    const int tid = threadIdx.x;
    const int mode = *modePtr;
    const float S = *S_total_f;
    const int P = *P_total;
    const float all_loss = S * (1.0f / 67100672.0f);  // N*(N-1)
    float avg = 0.f;
    if (mode == 2) {
        avg = S / (float)P;
    } else if (mode == 1 || mode == 3) {
        int C = *candCnt; if (C > CAND_CAP) C = CAND_CAP;
        for (int i = tid; i < C; i += 1024) vals[i] = cand[i];
        __syncthreads();
        const int K = C < HALFK ? C : HALFK;
        float s = 0.f;
        for (int i = tid; i < C; i += 1024) {
            float v = vals[i]; int g = 0;
            for (int j = 0; j < C; ++j) {   // all threads read same j -> LDS broadcast
                float u = vals[j];
                g += (u > v) || (u == v && j < i);   // deterministic tie-break
            }
            if (g < K) s += v;
        }
        #pragma unroll
        for (int off = 32; off > 0; off >>= 1) s += __shfl_down(s, off);
        if ((tid & 63) == 0) wsum[tid >> 6] = s;
        __syncthreads();
        if (tid == 0) {
            float t = 0.f;
            #pragma unroll
            for (int w = 0; w < 16; ++w) t += wsum[w];
            avg = (K > 0) ? t / (float)K : 0.f;
        }
    }
    if (tid == 0) { out[0] = avg; out[1] = all_loss; }
}

extern "C" void kernel_launch(void* const* d_in, const int* in_sizes, int n_in,
                              void* d_out, int out_size, void* d_ws, size_t ws_size,
                              hipStream_t stream)
{
    const float* p1 = (const float*)d_in[0];
    const float* p2 = (const float*)d_in[1];
    char* ws = (char*)d_ws;
    u16*   p1b  = (u16*)(ws + OFF_P1B);
    u16*   p2b  = (u16*)(ws + OFF_P2B);
    float* aArr = (float*)(ws + OFF_AARR);
    float* bArr = (float*)(ws + OFF_BARR);
    int*   hist = (int*)(ws + OFF_HIST);
    float* Sf   = (float*)(ws + OFF_CNT);
    int*   Pc   = (int*)(ws + OFF_CNT) + 1;
    int*   cc   = (int*)(ws + OFF_CNT) + 2;
    int*   mode = (int*)(ws + OFF_CNT) + 3;
    float* Tv   = (float*)(ws + OFF_CNT) + 4;
    float* cand = (float*)(ws + OFF_CAND);
    float* out  = (float*)d_out;

    init_kernel<<<256, 256, 0, stream>>>(hist);   // hist + counters contiguous
    prep_kernel<<<NROWS/4, 256, 0, stream>>>(p1, p2, p1b, p2b, aArr, bArr);
    dim3 grid(64, 64);
    pair_gemm<1><<<grid, 256, 0, stream>>>(p1b, p2b, aArr, bArr, Sf, Pc, hist, mode, Tv, cc, cand);
    scan_kernel<<<1, 256, 0, stream>>>(hist, Pc, mode, Tv);
    pair_gemm<3><<<grid, 256, 0, stream>>>(p1b, p2b, aArr, bArr, Sf, Pc, hist, mode, Tv, cc, cand);
    select_kernel<<<1, 1024, 0, stream>>>(mode, Sf, Pc, cc, cand, out);
}